// Round 1
// baseline (3933.876 us; speedup 1.0000x reference)
//
#include <hip/hip_runtime.h>

#define NN    140000   // total neurons
#define NTM1  20000    // Tm1 (clamped) neurons, type block 0
#define NTGT  120000   // simulated neurons (>= NTM1)
#define NE    2240000  // edges
#define NB    8        // batch
#define DT_   0.1f
#define STEPS 100
#define NBLK  469      // ceil(NTGT/256)

__global__ __launch_bounds__(256) void zero_counts(int* __restrict__ c) {
    int i = blockIdx.x * 256 + threadIdx.x;
    if (i < NTGT) c[i] = 0;
}

__global__ __launch_bounds__(256) void count_edges(const int* __restrict__ tgt,
                                                   int* __restrict__ counts) {
    int e = blockIdx.x * 256 + threadIdx.x;
    if (e < NE) {
        int t = tgt[e];
        if (t >= NTM1) atomicAdd(&counts[t - NTM1], 1);
    }
}

// Per-block exclusive scan (wave shuffle scan + LDS wave combine); writes
// local-exclusive into rp[i] and block total into bsum[blk].
__global__ __launch_bounds__(256) void scan_block(const int* __restrict__ counts,
                                                  int* __restrict__ rp,
                                                  int* __restrict__ bsum) {
    int tid  = threadIdx.x;
    int i    = blockIdx.x * 256 + tid;
    int lane = tid & 63;
    int wid  = tid >> 6;
    int x0 = (i < NTGT) ? counts[i] : 0;
    int x  = x0;
#pragma unroll
    for (int off = 1; off < 64; off <<= 1) {
        int y = __shfl_up(x, off);
        if (lane >= off) x += y;
    }
    __shared__ int wsum[4];
    if (lane == 63) wsum[wid] = x;
    __syncthreads();
    int woff = 0;
    for (int w = 0; w < wid; ++w) woff += wsum[w];
    if (i < NTGT) rp[i] = woff + x - x0;  // local exclusive
    if (tid == 0) bsum[blockIdx.x] = wsum[0] + wsum[1] + wsum[2] + wsum[3];
}

// Single-block scan of the 469 block sums; also writes rp[NTGT] = total.
__global__ __launch_bounds__(512) void scan_bsums(const int* __restrict__ bsum,
                                                  int* __restrict__ boff,
                                                  int* __restrict__ rp) {
    __shared__ int sd[512];
    int tid = threadIdx.x;
    int x = (tid < NBLK) ? bsum[tid] : 0;
    sd[tid] = x;
    __syncthreads();
    for (int off = 1; off < 512; off <<= 1) {
        int t = (tid >= off) ? sd[tid - off] : 0;
        __syncthreads();
        sd[tid] += t;
        __syncthreads();
    }
    if (tid < NBLK) boff[tid] = sd[tid] - x;   // exclusive block offset
    if (tid == 511) rp[NTGT] = sd[511];        // grand total
}

__global__ __launch_bounds__(256) void finalize_rp(int* __restrict__ rp,
                                                   const int* __restrict__ boff,
                                                   int* __restrict__ cursor) {
    int i = blockIdx.x * 256 + threadIdx.x;
    if (i < NTGT) {
        int f = rp[i] + boff[i >> 8];
        rp[i] = f;
        cursor[i] = f;   // fill cursors start at row begin
    }
}

__global__ __launch_bounds__(256) void fill_csr(const int* __restrict__ src,
                                                const int* __restrict__ tgt,
                                                const float* __restrict__ w,
                                                const float* __restrict__ p_se,
                                                const float* __restrict__ p_si,
                                                int* __restrict__ cursor,
                                                int* __restrict__ col,
                                                float* __restrict__ val) {
    int e = blockIdx.x * 256 + threadIdx.x;
    if (e >= NE) return;
    int t = tgt[e];
    if (t < NTM1) return;   // targets in the clamped block never matter
    float se = fmaxf(p_se[0], 0.f);
    float si = fmaxf(p_si[0], 0.f);
    float ww = w[e];
    float sc = ww > 0.f ? se : (ww < 0.f ? si : 1.f);
    int pos = atomicAdd(&cursor[t - NTM1], 1);
    col[pos] = src[e];
    val[pos] = ww * sc;
}

// v stored neuron-major: v[n*8 + b]. Tm1 block holds tm1_input (constant),
// simulated block starts at 0.
__global__ __launch_bounds__(256) void init_v(const float* __restrict__ tm1,
                                              float* __restrict__ vA,
                                              float* __restrict__ vB) {
    int n = blockIdx.x * 256 + threadIdx.x;
    if (n >= NN) return;
    if (n < NTM1) {
#pragma unroll
        for (int b = 0; b < NB; ++b) {
            float x = tm1[b * NTM1 + n];   // coalesced per-b
            vA[(size_t)n * NB + b] = x;
            vB[(size_t)n * NB + b] = x;
        }
    } else {
#pragma unroll
        for (int b = 0; b < NB; ++b) {
            vA[(size_t)n * NB + b] = 0.f;
            vB[(size_t)n * NB + b] = 0.f;
        }
    }
}

__global__ __launch_bounds__(256) void step_kernel(const float* __restrict__ vold,
                                                   float* __restrict__ vnew,
                                                   const int* __restrict__ rp,
                                                   const int* __restrict__ col,
                                                   const float* __restrict__ val,
                                                   const float* __restrict__ bias,
                                                   const float* __restrict__ taup) {
    int i = blockIdx.x * 256 + threadIdx.x;
    if (i >= NTGT) return;
    int n = NTM1 + i;
    int s = rp[i], e = rp[i + 1];

    float a0 = 0.f, a1 = 0.f, a2 = 0.f, a3 = 0.f,
          a4 = 0.f, a5 = 0.f, a6 = 0.f, a7 = 0.f;
    for (int k = s; k < e; ++k) {
        int   sidx = col[k];
        float wv   = val[k];
        const float4* vp = (const float4*)(vold + (size_t)sidx * NB);
        float4 p = vp[0];
        float4 q = vp[1];
        a0 += wv * fmaxf(p.x, 0.f);
        a1 += wv * fmaxf(p.y, 0.f);
        a2 += wv * fmaxf(p.z, 0.f);
        a3 += wv * fmaxf(p.w, 0.f);
        a4 += wv * fmaxf(q.x, 0.f);
        a5 += wv * fmaxf(q.y, 0.f);
        a6 += wv * fmaxf(q.z, 0.f);
        a7 += wv * fmaxf(q.w, 0.f);
    }

    float bsv  = bias[n];
    int   type = n / NTM1;                                   // 1..6
    float tau  = fminf(fmaxf(taup[type], 1.f), 100.f);
    float r    = DT_ / tau;

    const float4* vo = (const float4*)(vold + (size_t)n * NB);
    float4 o0 = vo[0], o1 = vo[1];
    float4 w0, w1;
    w0.x = o0.x + (a0 + bsv - o0.x) * r;
    w0.y = o0.y + (a1 + bsv - o0.y) * r;
    w0.z = o0.z + (a2 + bsv - o0.z) * r;
    w0.w = o0.w + (a3 + bsv - o0.w) * r;
    w1.x = o1.x + (a4 + bsv - o1.x) * r;
    w1.y = o1.y + (a5 + bsv - o1.y) * r;
    w1.z = o1.z + (a6 + bsv - o1.z) * r;
    w1.w = o1.w + (a7 + bsv - o1.w) * r;

    float4* vw = (float4*)(vnew + (size_t)n * NB);
    vw[0] = w0;
    vw[1] = w1;
}

// (N,8) -> (8,N) transpose into d_out; writes coalesced per batch row.
__global__ __launch_bounds__(256) void write_out(const float* __restrict__ v,
                                                 float* __restrict__ out) {
    int n = blockIdx.x * 256 + threadIdx.x;
    if (n >= NN) return;
#pragma unroll
    for (int b = 0; b < NB; ++b)
        out[(size_t)b * NN + n] = v[(size_t)n * NB + b];
}

extern "C" void kernel_launch(void* const* d_in, const int* in_sizes, int n_in,
                              void* d_out, int out_size, void* d_ws, size_t ws_size,
                              hipStream_t stream) {
    const float* tm1  = (const float*)d_in[0];
    const float* w    = (const float*)d_in[1];
    const float* bias = (const float*)d_in[2];
    const float* taup = (const float*)d_in[3];
    const float* p_se = (const float*)d_in[4];
    const float* p_si = (const float*)d_in[5];
    const int*   srci = (const int*)d_in[6];
    const int*   tgti = (const int*)d_in[7];
    float*       out  = (float*)d_out;

    char* ws = (char*)d_ws;
    size_t off = 0;
    auto alloc = [&](size_t bytes) -> char* {
        char* p = ws + off;
        off += (bytes + 255) & ~(size_t)255;
        return p;
    };
    float* vA     = (float*)alloc((size_t)NN * NB * 4);      // 4.48 MB
    float* vB     = (float*)alloc((size_t)NN * NB * 4);      // 4.48 MB
    int*   cursor = (int*)alloc((size_t)NTGT * 4);           // counts, then cursors
    int*   rp     = (int*)alloc(((size_t)NTGT + 1) * 4);
    int*   bsum   = (int*)alloc(512 * 4);
    int*   boff   = (int*)alloc(512 * 4);
    int*   col    = (int*)alloc((size_t)NE * 4);             // 8.96 MB
    float* val    = (float*)alloc((size_t)NE * 4);           // 8.96 MB
    // total ~28 MB of d_ws

    int ngrid = (NN + 255) / 256;     // 547
    int tgrid = (NTGT + 255) / 256;   // 469
    int egrid = (NE + 255) / 256;     // 8750

    // --- CSR-by-target build (amortized over 100 steps) ---
    zero_counts<<<tgrid, 256, 0, stream>>>(cursor);
    count_edges<<<egrid, 256, 0, stream>>>(tgti, cursor);
    scan_block<<<tgrid, 256, 0, stream>>>(cursor, rp, bsum);
    scan_bsums<<<1, 512, 0, stream>>>(bsum, boff, rp);
    finalize_rp<<<tgrid, 256, 0, stream>>>(rp, boff, cursor);
    fill_csr<<<egrid, 256, 0, stream>>>(srci, tgti, w, p_se, p_si, cursor, col, val);
    init_v<<<ngrid, 256, 0, stream>>>(tm1, vA, vB);

    // --- 100 ping-pong steps ---
    float* cur = vA;
    float* nxt = vB;
    for (int s = 0; s < STEPS; ++s) {
        step_kernel<<<tgrid, 256, 0, stream>>>(cur, nxt, rp, col, val, bias, taup);
        float* t = cur; cur = nxt; nxt = t;
    }

    write_out<<<ngrid, 256, 0, stream>>>(cur, out);
}

// Round 3
// 2295.100 us; speedup vs baseline: 1.7140x; 1.7140x over previous
//
#include <hip/hip_runtime.h>

#define NN    140000   // total neurons
#define NTM1  20000    // Tm1 (clamped) neurons, type block 0
#define NTGT  120000   // simulated neurons
#define NE    2240000  // edges
#define NB    8        // batch
#define DT_   0.1f
#define STEPS 100
#define NBLK  469      // ceil(NTGT/256)

__global__ __launch_bounds__(256) void zero_counts(int* __restrict__ c) {
    int i = blockIdx.x * 256 + threadIdx.x;
    if (i < NTGT) c[i] = 0;
}

__global__ __launch_bounds__(256) void count_edges(const int* __restrict__ tgt,
                                                   int* __restrict__ counts) {
    int e = blockIdx.x * 256 + threadIdx.x;
    if (e < NE) {
        int t = tgt[e];
        if (t >= NTM1) atomicAdd(&counts[t - NTM1], 1);
    }
}

// Per-block exclusive scan; local-exclusive into rp[i], block total into bsum.
__global__ __launch_bounds__(256) void scan_block(const int* __restrict__ counts,
                                                  int* __restrict__ rp,
                                                  int* __restrict__ bsum) {
    int tid  = threadIdx.x;
    int i    = blockIdx.x * 256 + tid;
    int lane = tid & 63;
    int wid  = tid >> 6;
    int x0 = (i < NTGT) ? counts[i] : 0;
    int x  = x0;
#pragma unroll
    for (int off = 1; off < 64; off <<= 1) {
        int y = __shfl_up(x, off);
        if (lane >= off) x += y;
    }
    __shared__ int wsum[4];
    if (lane == 63) wsum[wid] = x;
    __syncthreads();
    int woff = 0;
    for (int w = 0; w < wid; ++w) woff += wsum[w];
    if (i < NTGT) rp[i] = woff + x - x0;  // local exclusive
    if (tid == 0) bsum[blockIdx.x] = wsum[0] + wsum[1] + wsum[2] + wsum[3];
}

__global__ __launch_bounds__(512) void scan_bsums(const int* __restrict__ bsum,
                                                  int* __restrict__ boff,
                                                  int* __restrict__ rp) {
    __shared__ int sd[512];
    int tid = threadIdx.x;
    int x = (tid < NBLK) ? bsum[tid] : 0;
    sd[tid] = x;
    __syncthreads();
    for (int off = 1; off < 512; off <<= 1) {
        int t = (tid >= off) ? sd[tid - off] : 0;
        __syncthreads();
        sd[tid] += t;
        __syncthreads();
    }
    if (tid < NBLK) boff[tid] = sd[tid] - x;   // exclusive block offset
    if (tid == 511) rp[NTGT] = sd[511];        // grand total
}

__global__ __launch_bounds__(256) void finalize_rp(int* __restrict__ rp,
                                                   const int* __restrict__ boff,
                                                   int* __restrict__ cursor) {
    int i = blockIdx.x * 256 + threadIdx.x;
    if (i < NTGT) {
        int f = rp[i] + boff[i >> 8];
        rp[i] = f;
        cursor[i] = f;
    }
}

// Packed edge record: .x = bitcast(source index), .y = pre-scaled weight.
__global__ __launch_bounds__(256) void fill_csr(const int* __restrict__ src,
                                                const int* __restrict__ tgt,
                                                const float* __restrict__ w,
                                                const float* __restrict__ p_se,
                                                const float* __restrict__ p_si,
                                                int* __restrict__ cursor,
                                                float2* __restrict__ e2) {
    int e = blockIdx.x * 256 + threadIdx.x;
    if (e >= NE) return;
    int t = tgt[e];
    if (t < NTM1) return;   // targets in the clamped block never matter
    float se = fmaxf(p_se[0], 0.f);
    float si = fmaxf(p_si[0], 0.f);
    float ww = w[e];
    float sc = ww > 0.f ? se : (ww < 0.f ? si : 1.f);
    int pos = atomicAdd(&cursor[t - NTM1], 1);
    e2[pos] = make_float2(__int_as_float(src[e]), ww * sc);
}

// v stored neuron-major: v[n*8 + b].
__global__ __launch_bounds__(256) void init_v(const float* __restrict__ tm1,
                                              float* __restrict__ vA,
                                              float* __restrict__ vB) {
    int n = blockIdx.x * 256 + threadIdx.x;
    if (n >= NN) return;
    if (n < NTM1) {
#pragma unroll
        for (int b = 0; b < NB; ++b) {
            float x = tm1[b * NTM1 + n];
            vA[(size_t)n * NB + b] = x;
            vB[(size_t)n * NB + b] = x;
        }
    } else {
#pragma unroll
        for (int b = 0; b < NB; ++b) {
            vA[(size_t)n * NB + b] = 0.f;
            vB[(size_t)n * NB + b] = 0.f;
        }
    }
}

// 8 lanes cooperate on one target row; 32 rows per 256-thread block.
__global__ __launch_bounds__(256) void step_kernel(const float* __restrict__ vold,
                                                   float* __restrict__ vnew,
                                                   const int* __restrict__ rp,
                                                   const float2* __restrict__ e2,
                                                   const float* __restrict__ bias,
                                                   const float* __restrict__ taup) {
    int sub = threadIdx.x & 7;
    int row = blockIdx.x * 32 + (threadIdx.x >> 3);
    if (row >= NTGT) return;
    int n = NTM1 + row;
    int s = rp[row], e = rp[row + 1];

    float a0 = 0.f, a1 = 0.f, a2 = 0.f, a3 = 0.f,
          a4 = 0.f, a5 = 0.f, a6 = 0.f, a7 = 0.f;
    for (int k = s + sub; k < e; k += 8) {
        float2 ev = e2[k];                 // 8 lanes -> 64B coalesced
        int   sidx = __float_as_int(ev.x);
        float wv   = ev.y;
        const float4* vp = (const float4*)(vold + (size_t)sidx * NB);
        float4 p = vp[0];
        float4 q = vp[1];
        a0 += wv * fmaxf(p.x, 0.f);
        a1 += wv * fmaxf(p.y, 0.f);
        a2 += wv * fmaxf(p.z, 0.f);
        a3 += wv * fmaxf(p.w, 0.f);
        a4 += wv * fmaxf(q.x, 0.f);
        a5 += wv * fmaxf(q.y, 0.f);
        a6 += wv * fmaxf(q.z, 0.f);
        a7 += wv * fmaxf(q.w, 0.f);
    }

    // Butterfly reduce-scatter across the 8 lanes: lane `sub` ends with batch `sub`.
    bool hi4 = (sub & 4) != 0;
    {
        float s0 = hi4 ? a0 : a4;
        float s1 = hi4 ? a1 : a5;
        float s2 = hi4 ? a2 : a6;
        float s3 = hi4 ? a3 : a7;
        s0 = __shfl_xor(s0, 4);
        s1 = __shfl_xor(s1, 4);
        s2 = __shfl_xor(s2, 4);
        s3 = __shfl_xor(s3, 4);
        a0 = (hi4 ? a4 : a0) + s0;
        a1 = (hi4 ? a5 : a1) + s1;
        a2 = (hi4 ? a6 : a2) + s2;
        a3 = (hi4 ? a7 : a3) + s3;
    }
    bool hi2 = (sub & 2) != 0;
    {
        float s0 = hi2 ? a0 : a2;
        float s1 = hi2 ? a1 : a3;
        s0 = __shfl_xor(s0, 2);
        s1 = __shfl_xor(s1, 2);
        a0 = (hi2 ? a2 : a0) + s0;
        a1 = (hi2 ? a3 : a1) + s1;
    }
    bool hi1 = (sub & 1) != 0;
    {
        float s0 = hi1 ? a0 : a1;
        s0 = __shfl_xor(s0, 1);
        a0 = (hi1 ? a1 : a0) + s0;
    }
    // a0 now holds the synaptic sum for batch `sub` of row n.

    float bsv  = bias[n];
    int   type = n / NTM1;                       // 1..6 (const-divide -> magic mul)
    float tau  = fminf(fmaxf(taup[type], 1.f), 100.f);
    float r    = DT_ / tau;

    float o = vold[(size_t)n * NB + sub];        // coalesced 32B per row-group
    vnew[(size_t)n * NB + sub] = o + (a0 + bsv - o) * r;
}

// (N,8) -> (8,N) transpose into d_out.
__global__ __launch_bounds__(256) void write_out(const float* __restrict__ v,
                                                 float* __restrict__ out) {
    int n = blockIdx.x * 256 + threadIdx.x;
    if (n >= NN) return;
#pragma unroll
    for (int b = 0; b < NB; ++b)
        out[(size_t)b * NN + n] = v[(size_t)n * NB + b];
}

extern "C" void kernel_launch(void* const* d_in, const int* in_sizes, int n_in,
                              void* d_out, int out_size, void* d_ws, size_t ws_size,
                              hipStream_t stream) {
    const float* tm1  = (const float*)d_in[0];
    const float* w    = (const float*)d_in[1];
    const float* bias = (const float*)d_in[2];
    const float* taup = (const float*)d_in[3];
    const float* p_se = (const float*)d_in[4];
    const float* p_si = (const float*)d_in[5];
    const int*   srci = (const int*)d_in[6];
    const int*   tgti = (const int*)d_in[7];
    float*       out  = (float*)d_out;

    char* ws = (char*)d_ws;
    size_t off = 0;
    auto alloc = [&](size_t bytes) -> char* {
        char* p = ws + off;
        off += (bytes + 255) & ~(size_t)255;
        return p;
    };
    float*  vA     = (float*)alloc((size_t)NN * NB * 4);     // 4.48 MB
    float*  vB     = (float*)alloc((size_t)NN * NB * 4);     // 4.48 MB
    int*    cursor = (int*)alloc((size_t)NTGT * 4);
    int*    rp     = (int*)alloc(((size_t)NTGT + 1) * 4);
    int*    bsum   = (int*)alloc(512 * 4);
    int*    boff   = (int*)alloc(512 * 4);
    float2* e2     = (float2*)alloc((size_t)NE * 8);         // 17.9 MB packed edges

    int ngrid = (NN + 255) / 256;     // 547
    int tgrid = (NTGT + 255) / 256;   // 469
    int egrid = (NE + 255) / 256;     // 8750
    int sgrid = (NTGT + 31) / 32;     // 3750 (8 lanes per row)

    // --- CSR-by-target build (amortized over 100 steps) ---
    zero_counts<<<tgrid, 256, 0, stream>>>(cursor);
    count_edges<<<egrid, 256, 0, stream>>>(tgti, cursor);
    scan_block<<<tgrid, 256, 0, stream>>>(cursor, rp, bsum);
    scan_bsums<<<1, 512, 0, stream>>>(bsum, boff, rp);
    finalize_rp<<<tgrid, 256, 0, stream>>>(rp, boff, cursor);
    fill_csr<<<egrid, 256, 0, stream>>>(srci, tgti, w, p_se, p_si, cursor, e2);
    init_v<<<ngrid, 256, 0, stream>>>(tm1, vA, vB);

    // --- 100 ping-pong steps ---
    float* cur = vA;
    float* nxt = vB;
    for (int s = 0; s < STEPS; ++s) {
        step_kernel<<<sgrid, 256, 0, stream>>>(cur, nxt, rp, e2, bias, taup);
        float* t = cur; cur = nxt; nxt = t;
    }

    write_out<<<ngrid, 256, 0, stream>>>(cur, out);
}